// Round 1
// baseline (463.006 us; speedup 1.0000x reference)
//
#include <hip/hip_runtime.h>
#include <cmath>

#define G_NUM 128
#define NPTS  128
#define FDIM  128
#define KNNK  24
#define NTOT  (G_NUM*NPTS)   // 16384

__device__ __forceinline__ float eluf(float x){ return x > 0.0f ? x : expm1f(x); }

// ---------------------------------------------------------------------------
// prep: Wcat[l][k][0:128] = Wtop-Wbot ; Wcat[l][k][128:256] = Wbot ; bias256
// ---------------------------------------------------------------------------
__global__ void prep_kernel(const float* __restrict__ w1, const float* __restrict__ w2,
                            const float* __restrict__ w3,
                            const float* __restrict__ b1, const float* __restrict__ b2,
                            const float* __restrict__ b3,
                            float* __restrict__ wcat, float* __restrict__ bias)
{
    int e = blockIdx.x * 256 + threadIdx.x;
    if (e < 3 * 128 * 128) {
        int l = e >> 14;
        int r = e & 16383;
        int k = r >> 7;
        int h = r & 127;
        const float* w = (l == 0) ? w1 : ((l == 1) ? w2 : w3);
        float wt = w[k * 128 + h];
        float wb = w[(128 + k) * 128 + h];
        float* wc = wcat + l * 128 * 256;
        wc[k * 256 + h]       = wt - wb;
        wc[k * 256 + 128 + h] = wb;
    }
    if (e < 3 * 256) {
        int l = e >> 8, j = e & 255;
        const float* b = (l == 0) ? b1 : ((l == 1) ? b2 : b3);
        bias[l * 256 + j] = (j < 128) ? b[j] : 0.0f;
    }
}

// ---------------------------------------------------------------------------
// GEMM: C[M x N] = act(A[M x KD] @ B[KD x N] + bias), 64x64 tile, 4x4 micro.
// A-tile stored transposed [k][m] with float4-unit XOR swizzle (conflict-free
// float4 reads); B-tile [k][n] natural.
// ---------------------------------------------------------------------------
template<int KD, int DOELU>
__global__ __launch_bounds__(256) void gemm_kernel(const float* __restrict__ A,
                                                   const float* __restrict__ B,
                                                   const float* __restrict__ bias,
                                                   float* __restrict__ C, int N)
{
    extern __shared__ float sm[];
    float* At = sm;              // [KD][64] swizzled
    float* Bs = sm + KD * 64;    // [KD][64]
    const int tid = threadIdx.x;
    const int m0 = blockIdx.x * 64, n0 = blockIdx.y * 64;

    // stage A (global coalesced along k), swizzled transpose into LDS
    for (int e = tid; e < 64 * KD; e += 256) {
        int k = e % KD, m = e / KD;
        int um = (m >> 2) ^ (k & 15);
        At[k * 64 + (um << 2) + (m & 3)] = A[(size_t)(m0 + m) * KD + k];
    }
    // stage B (global coalesced along n)
    for (int e = tid; e < KD * 64; e += 256) {
        int k = e >> 6, n = e & 63;
        Bs[k * 64 + n] = B[(size_t)k * N + n0 + n];
    }
    __syncthreads();

    const int tml = tid & 15;            // m-unit index
    const int tn  = (tid >> 4) * 4;
    float acc[4][4] = {};
    #pragma unroll 4
    for (int k = 0; k < KD; ++k) {
        const float4 av = *reinterpret_cast<const float4*>(&At[k * 64 + ((tml ^ (k & 15)) << 2)]);
        const float4 bv = *reinterpret_cast<const float4*>(&Bs[k * 64 + tn]);
        acc[0][0] += av.x * bv.x; acc[0][1] += av.x * bv.y; acc[0][2] += av.x * bv.z; acc[0][3] += av.x * bv.w;
        acc[1][0] += av.y * bv.x; acc[1][1] += av.y * bv.y; acc[1][2] += av.y * bv.z; acc[1][3] += av.y * bv.w;
        acc[2][0] += av.z * bv.x; acc[2][1] += av.z * bv.y; acc[2][2] += av.z * bv.z; acc[2][3] += av.z * bv.w;
        acc[3][0] += av.w * bv.x; acc[3][1] += av.w * bv.y; acc[3][2] += av.w * bv.z; acc[3][3] += av.w * bv.w;
    }
    const int tm = tml * 4;
    #pragma unroll
    for (int u = 0; u < 4; ++u) {
        float4 o;
        o.x = acc[u][0] + bias[n0 + tn + 0];
        o.y = acc[u][1] + bias[n0 + tn + 1];
        o.z = acc[u][2] + bias[n0 + tn + 2];
        o.w = acc[u][3] + bias[n0 + tn + 3];
        if (DOELU) { o.x = eluf(o.x); o.y = eluf(o.y); o.z = eluf(o.z); o.w = eluf(o.w); }
        *reinterpret_cast<float4*>(&C[(size_t)(m0 + tm + u) * N + n0 + tn]) = o;
    }
}

// ---------------------------------------------------------------------------
// edgeconv: per-graph. d2 -> knn(24) -> out = elu(a_i + max_j c_j), in-place h.
// LDS: Xs[128][129] (reused as Cs[128][128]) | D[128][129] | Sq[128] | idx[128][24]
// ---------------------------------------------------------------------------
__global__ __launch_bounds__(256) void edgeconv_kernel(float* __restrict__ h,
                                                       const float* __restrict__ ac)
{
    extern __shared__ float sm[];
    float* Xs  = sm;                          // [128][129]
    float* D   = sm + 128 * 129;              // [128][129]
    float* Sq  = sm + 2 * 128 * 129;          // [128]
    int*   idx = (int*)(sm + 2 * 128 * 129 + 128); // [128][24]
    float* Cs  = sm;                          // [128][128] aliases Xs (dead after d2)

    const int g = blockIdx.x, tid = threadIdx.x;
    float* hg = h + (size_t)g * NPTS * FDIM;
    const float* acg = ac + (size_t)g * NPTS * 256;

    // stage X
    for (int e = tid; e < NPTS * FDIM; e += 256) {
        int m = e >> 7, k = e & 127;
        Xs[m * 129 + k] = hg[e];
    }
    __syncthreads();

    // per-point squared norms
    if (tid < 128) {
        float s = 0.0f;
        #pragma unroll 8
        for (int k = 0; k < 128; ++k) { float v = Xs[tid * 129 + k]; s += v * v; }
        Sq[tid] = s;
    }
    __syncthreads();

    // d2 = sq_i + sq_j - 2 * x_i . x_j   (8x8 per thread)
    {
        const int ti = (tid & 15) * 8, tj = (tid >> 4) * 8;
        float acc[8][8] = {};
        #pragma unroll 2
        for (int k = 0; k < 128; ++k) {
            float av[8], bv[8];
            #pragma unroll
            for (int u = 0; u < 8; ++u) av[u] = Xs[(ti + u) * 129 + k];
            #pragma unroll
            for (int v = 0; v < 8; ++v) bv[v] = Xs[(tj + v) * 129 + k];
            #pragma unroll
            for (int u = 0; u < 8; ++u)
                #pragma unroll
                for (int v = 0; v < 8; ++v)
                    acc[u][v] += av[u] * bv[v];
        }
        #pragma unroll
        for (int u = 0; u < 8; ++u)
            #pragma unroll
            for (int v = 0; v < 8; ++v)
                D[(ti + u) * 129 + (tj + v)] = Sq[ti + u] + Sq[tj + v] - 2.0f * acc[u][v];
    }
    __syncthreads();

    // waves 0-1: knn per row (24-pass min-scan, 4 sub-chains, tie -> lowest j)
    // waves 2-3: concurrently stage Cs = c-graph into LDS (Xs region, dead)
    if (tid < 128) {
        float* drow = &D[tid * 129];
        #pragma unroll 1
        for (int t = 0; t < KNNK; ++t) {
            float mv0 = 3.0e38f, mv1 = 3.0e38f, mv2 = 3.0e38f, mv3 = 3.0e38f;
            int   mj0 = 0, mj1 = 32, mj2 = 64, mj3 = 96;
            #pragma unroll 8
            for (int j = 0; j < 32; ++j) {
                float v0 = drow[j];      if (v0 < mv0) { mv0 = v0; mj0 = j; }
                float v1 = drow[j + 32]; if (v1 < mv1) { mv1 = v1; mj1 = j + 32; }
                float v2 = drow[j + 64]; if (v2 < mv2) { mv2 = v2; mj2 = j + 64; }
                float v3 = drow[j + 96]; if (v3 < mv3) { mv3 = v3; mj3 = j + 96; }
            }
            if (mv1 < mv0) { mv0 = mv1; mj0 = mj1; }
            if (mv3 < mv2) { mv2 = mv3; mj2 = mj3; }
            if (mv2 < mv0) { mv0 = mv2; mj0 = mj2; }
            idx[tid * KNNK + t] = mj0;
            drow[mj0] = 3.0e38f;
        }
    } else {
        const int t2 = tid & 127;
        for (int e = t2; e < NPTS * FDIM; e += 128) {
            int j = e >> 7, hh = e & 127;
            Cs[j * 128 + hh] = acg[j * 256 + 128 + hh];
        }
    }
    __syncthreads();

    // combine: out[i][h] = elu(a[i][h] + max_t Cs[idx[i][t]][h])  (elu monotonic)
    {
        const int q = tid >> 6, h2 = (tid & 63) * 2;
        for (int i = q * 32; i < q * 32 + 32; ++i) {
            const int* jr = &idx[i * KNNK];
            float mc0 = -3.0e38f, mc1 = -3.0e38f;
            #pragma unroll
            for (int t = 0; t < KNNK; ++t) {
                int j = jr[t];
                float2 cv = *reinterpret_cast<const float2*>(&Cs[j * 128 + h2]);
                mc0 = fmaxf(mc0, cv.x);
                mc1 = fmaxf(mc1, cv.y);
            }
            float2 av = *reinterpret_cast<const float2*>(&acg[i * 256 + h2]);
            float2 o;
            o.x = eluf(av.x + mc0);
            o.y = eluf(av.y + mc1);
            *reinterpret_cast<float2*>(&hg[i * 128 + h2]) = o;
        }
    }
}

// ---------------------------------------------------------------------------
// head: per-graph sum-pool + 128->64->32->32->6 MLP (elu except last)
// ---------------------------------------------------------------------------
__global__ __launch_bounds__(128) void head_kernel(const float* __restrict__ h,
        const float* __restrict__ w1, const float* __restrict__ b1,
        const float* __restrict__ w2, const float* __restrict__ b2,
        const float* __restrict__ w3, const float* __restrict__ b3,
        const float* __restrict__ w4, const float* __restrict__ b4,
        float* __restrict__ out)
{
    __shared__ float pooled[128], s1[64], s2[32], s3[32];
    const int g = blockIdx.x, t = threadIdx.x;
    const float* hg = h + (size_t)g * NPTS * FDIM;
    float s = 0.0f;
    for (int p = 0; p < 128; ++p) s += hg[p * 128 + t];
    pooled[t] = s;
    __syncthreads();
    if (t < 64) {
        float a = b1[t];
        #pragma unroll 8
        for (int k = 0; k < 128; ++k) a += pooled[k] * w1[k * 64 + t];
        s1[t] = eluf(a);
    }
    __syncthreads();
    if (t < 32) {
        float a = b2[t];
        #pragma unroll 8
        for (int k = 0; k < 64; ++k) a += s1[k] * w2[k * 32 + t];
        s2[t] = eluf(a);
    }
    __syncthreads();
    if (t < 32) {
        float a = b3[t];
        #pragma unroll 8
        for (int k = 0; k < 32; ++k) a += s2[k] * w3[k * 32 + t];
        s3[t] = eluf(a);
    }
    __syncthreads();
    if (t < 6) {
        float a = b4[t];
        #pragma unroll 8
        for (int k = 0; k < 32; ++k) a += s3[k] * w4[k * 6 + t];
        out[g * 6 + t] = a;
    }
}

__global__ void batch_kernel(const int* __restrict__ bpf, float* __restrict__ out)
{
    int i = blockIdx.x * 256 + threadIdx.x;
    if (i < NTOT) out[768 + i] = (float)bpf[i];
}

// ---------------------------------------------------------------------------
extern "C" void kernel_launch(void* const* d_in, const int* in_sizes, int n_in,
                              void* d_out, int out_size, void* d_ws, size_t ws_size,
                              hipStream_t stream)
{
    const float* x_pf   = (const float*)d_in[0];
    const float* enc_w1 = (const float*)d_in[1];
    const float* enc_b1 = (const float*)d_in[2];
    const float* enc_w2 = (const float*)d_in[3];
    const float* enc_b2 = (const float*)d_in[4];
    const float* c1w = (const float*)d_in[5];
    const float* c1b = (const float*)d_in[6];
    const float* c2w = (const float*)d_in[7];
    const float* c2b = (const float*)d_in[8];
    const float* c3w = (const float*)d_in[9];
    const float* c3b = (const float*)d_in[10];
    const float* o_w1 = (const float*)d_in[11];
    const float* o_b1 = (const float*)d_in[12];
    const float* o_w2 = (const float*)d_in[13];
    const float* o_b2 = (const float*)d_in[14];
    const float* o_w3 = (const float*)d_in[15];
    const float* o_b3 = (const float*)d_in[16];
    const float* o_w4 = (const float*)d_in[17];
    const float* o_b4 = (const float*)d_in[18];
    const int*   bpf  = (const int*)d_in[19];
    float* out = (float*)d_out;

    float* ws   = (float*)d_ws;
    float* h    = ws;                       // 16384*128
    float* ac   = ws + (size_t)NTOT * FDIM; // 16384*256 (also enc intermediate)
    float* wcat = ac + (size_t)NTOT * 256;  // 3*128*256
    float* bias = wcat + 3 * 128 * 256;     // 3*256

    prep_kernel<<<192, 256, 0, stream>>>(c1w, c2w, c3w, c1b, c2b, c3b, wcat, bias);

    // encoder: x(16384x16) -> h1(ac) -> h
    gemm_kernel<16, 1><<<dim3(NTOT / 64, 2), 256, (16 * 64 + 16 * 64) * 4, stream>>>(
        x_pf, enc_w1, enc_b1, ac, 128);
    gemm_kernel<128, 1><<<dim3(NTOT / 64, 2), 256, (128 * 64 + 128 * 64) * 4, stream>>>(
        ac, enc_w2, enc_b2, h, 128);

    const size_t convLds = (size_t)(2 * 128 * 129 + 128) * 4 + 128 * KNNK * 4;
    for (int l = 0; l < 3; ++l) {
        gemm_kernel<128, 0><<<dim3(NTOT / 64, 4), 256, (128 * 64 + 128 * 64) * 4, stream>>>(
            h, wcat + l * 128 * 256, bias + l * 256, ac, 256);
        edgeconv_kernel<<<G_NUM, 256, convLds, stream>>>(h, ac);
    }

    head_kernel<<<G_NUM, 128, 0, stream>>>(h, o_w1, o_b1, o_w2, o_b2, o_w3, o_b3,
                                           o_w4, o_b4, out);
    batch_kernel<<<64, 256, 0, stream>>>(bpf, out);
}